// Round 1
// baseline (368.157 us; speedup 1.0000x reference)
//
#include <hip/hip_runtime.h>
#include <math.h>

// Problem constants (from reference): B=32, L=2048, D_ENC=D_DEC=1024.
#define BB     32
#define LL     2048
#define DD     1024
#define SPLIT  32                     // L-chunks per batch
#define WAVES  4
#define THREADS (WAVES * 64)
#define ROWS_PER_BLOCK (LL / SPLIT)   // 64
#define ROWS_PER_WAVE  (ROWS_PER_BLOCK / WAVES) // 16

// Workspace layout (floats):
//   part_c : [B][SPLIT][D]   = 32*32*1024 = 4 MiB
//   part_ms: [B][SPLIT][2]   (m, s)
#define PART_C_ELEMS ((size_t)BB * SPLIT * DD)

// ---------------------------------------------------------------------------
// Kernel 1: per-(batch, chunk) online-softmax partial.
// Softmax is shift-invariant, so the per-batch decoder term (dec·w_dec + b)
// cancels — we only need enc·w_enc. Each row of enc is read ONCE; the same
// registers feed the logit dot-product and the context accumulation.
// ---------------------------------------------------------------------------
__global__ __launch_bounds__(THREADS) void attn_partial(
    const float* __restrict__ enc, const float* __restrict__ W,
    float* __restrict__ part_c, float* __restrict__ part_ms)
{
    const int lane  = threadIdx.x & 63;
    const int wv    = threadIdx.x >> 6;
    const int chunk = blockIdx.x;
    const int bb    = blockIdx.y;

    // w_enc slice for this lane: d = j*256 + 4*lane + i, j = 0..3
    const float4* w4 = (const float4*)W; // W[0:1024] = w_enc
    const float4 w0 = w4[lane];
    const float4 w1 = w4[64  + lane];
    const float4 w2 = w4[128 + lane];
    const float4 w3 = w4[192 + lane];

    float m = -3.0e38f, s = 0.0f;
    float4 a0 = make_float4(0.f,0.f,0.f,0.f);
    float4 a1 = a0, a2 = a0, a3 = a0;

    const int row0 = chunk * ROWS_PER_BLOCK + wv * ROWS_PER_WAVE;
    const float4* base = (const float4*)enc + ((size_t)bb * LL + row0) * (DD / 4);

    for (int r = 0; r < ROWS_PER_WAVE; ++r) {
        const float4* rp = base + (size_t)r * (DD / 4);
        const float4 r0 = rp[lane];
        const float4 r1 = rp[64  + lane];
        const float4 r2 = rp[128 + lane];
        const float4 r3 = rp[192 + lane];

        float p = r0.x*w0.x + r0.y*w0.y + r0.z*w0.z + r0.w*w0.w
                + r1.x*w1.x + r1.y*w1.y + r1.z*w1.z + r1.w*w1.w
                + r2.x*w2.x + r2.y*w2.y + r2.z*w2.z + r2.w*w2.w
                + r3.x*w3.x + r3.y*w3.y + r3.z*w3.z + r3.w*w3.w;

        // wave-wide reduce (64 lanes)
        #pragma unroll
        for (int off = 32; off > 0; off >>= 1)
            p += __shfl_xor(p, off, 64);

        const float mn    = fmaxf(m, p);
        const float alpha = __expf(m - mn);   // 0 on first iter (m = -3e38)
        const float e     = __expf(p - mn);
        s = s * alpha + e;
        a0.x = a0.x*alpha + e*r0.x;  a0.y = a0.y*alpha + e*r0.y;
        a0.z = a0.z*alpha + e*r0.z;  a0.w = a0.w*alpha + e*r0.w;
        a1.x = a1.x*alpha + e*r1.x;  a1.y = a1.y*alpha + e*r1.y;
        a1.z = a1.z*alpha + e*r1.z;  a1.w = a1.w*alpha + e*r1.w;
        a2.x = a2.x*alpha + e*r2.x;  a2.y = a2.y*alpha + e*r2.y;
        a2.z = a2.z*alpha + e*r2.z;  a2.w = a2.w*alpha + e*r2.w;
        a3.x = a3.x*alpha + e*r3.x;  a3.y = a3.y*alpha + e*r3.y;
        a3.z = a3.z*alpha + e*r3.z;  a3.w = a3.w*alpha + e*r3.w;
        m = mn;
    }

    // ---- combine the 4 waves of this block in LDS ----
    __shared__ float red_m[WAVES], red_s[WAVES];
    __shared__ float lacc[DD];
    if (lane == 0) { red_m[wv] = m; red_s[wv] = s; }
    __syncthreads();

    const float M = fmaxf(fmaxf(red_m[0], red_m[1]), fmaxf(red_m[2], red_m[3]));
    float S = 0.0f;
    #pragma unroll
    for (int w = 0; w < WAVES; ++w) S += __expf(red_m[w] - M) * red_s[w];

    const float al = __expf(m - M);
    float4* l4 = (float4*)lacc;
    if (wv == 0) {
        float4 t;
        t.x = al*a0.x; t.y = al*a0.y; t.z = al*a0.z; t.w = al*a0.w; l4[lane]       = t;
        t.x = al*a1.x; t.y = al*a1.y; t.z = al*a1.z; t.w = al*a1.w; l4[64  + lane] = t;
        t.x = al*a2.x; t.y = al*a2.y; t.z = al*a2.z; t.w = al*a2.w; l4[128 + lane] = t;
        t.x = al*a3.x; t.y = al*a3.y; t.z = al*a3.z; t.w = al*a3.w; l4[192 + lane] = t;
    }
    __syncthreads();
    #pragma unroll
    for (int w = 1; w < WAVES; ++w) {
        if (wv == w) {
            float4 t;
            t = l4[lane];       t.x += al*a0.x; t.y += al*a0.y; t.z += al*a0.z; t.w += al*a0.w; l4[lane]       = t;
            t = l4[64  + lane]; t.x += al*a1.x; t.y += al*a1.y; t.z += al*a1.z; t.w += al*a1.w; l4[64  + lane] = t;
            t = l4[128 + lane]; t.x += al*a2.x; t.y += al*a2.y; t.z += al*a2.z; t.w += al*a2.w; l4[128 + lane] = t;
            t = l4[192 + lane]; t.x += al*a3.x; t.y += al*a3.y; t.z += al*a3.z; t.w += al*a3.w; l4[192 + lane] = t;
        }
        __syncthreads();
    }

    // write block partial
    const int pidx = bb * SPLIT + chunk;
    float4* pc = (float4*)part_c + (size_t)pidx * (DD / 4);
    for (int i = threadIdx.x; i < DD / 4; i += THREADS) pc[i] = l4[i];
    if (threadIdx.x == 0) {
        part_ms[2 * pidx + 0] = M;
        part_ms[2 * pidx + 1] = S;
    }
}

// ---------------------------------------------------------------------------
// Kernel 2: combine SPLIT partials per batch, normalize, write context.
// ---------------------------------------------------------------------------
__global__ __launch_bounds__(256) void attn_combine(
    const float* __restrict__ part_c, const float* __restrict__ part_ms,
    float* __restrict__ out)
{
    const int bb = blockIdx.x;
    const int t  = threadIdx.x;

    float M = -3.0e38f;
    #pragma unroll
    for (int p = 0; p < SPLIT; ++p)
        M = fmaxf(M, part_ms[2 * (bb * SPLIT + p) + 0]);

    float wgt[SPLIT];
    float S = 0.0f;
    #pragma unroll
    for (int p = 0; p < SPLIT; ++p) {
        const float mp = part_ms[2 * (bb * SPLIT + p) + 0];
        const float sp = part_ms[2 * (bb * SPLIT + p) + 1];
        wgt[p] = __expf(mp - M);
        S += wgt[p] * sp;
    }
    const float inv = 1.0f / S;

    // each thread owns one float4 of D (256 threads * 4 = 1024)
    float4 acc = make_float4(0.f,0.f,0.f,0.f);
    #pragma unroll
    for (int p = 0; p < SPLIT; ++p) {
        const float4 c = ((const float4*)part_c)[((size_t)(bb * SPLIT + p)) * (DD/4) + t];
        acc.x += wgt[p] * c.x; acc.y += wgt[p] * c.y;
        acc.z += wgt[p] * c.z; acc.w += wgt[p] * c.w;
    }
    acc.x *= inv; acc.y *= inv; acc.z *= inv; acc.w *= inv;
    ((float4*)out)[bb * (DD/4) + t] = acc;
}

extern "C" void kernel_launch(void* const* d_in, const int* in_sizes, int n_in,
                              void* d_out, int out_size, void* d_ws, size_t ws_size,
                              hipStream_t stream) {
    const float* enc = (const float*)d_in[0];  // (32, 2048, 1024) fp32
    // d_in[1] = decoder_hidden — cancels under softmax (constant per batch)
    const float* W   = (const float*)d_in[2];  // (2048, 1) fp32; first 1024 = w_enc
    // d_in[3] = b — also cancels
    float* out = (float*)d_out;                // (32, 1, 1024) fp32

    float* part_c  = (float*)d_ws;
    float* part_ms = part_c + PART_C_ELEMS;

    dim3 grid1(SPLIT, BB);
    attn_partial<<<grid1, THREADS, 0, stream>>>(enc, W, part_c, part_ms);
    attn_combine<<<BB, 256, 0, stream>>>(part_c, part_ms, out);
}